// Round 10
// baseline (452.258 us; speedup 1.0000x reference)
//
#include <hip/hip_runtime.h>
#include <hip/hip_bf16.h>

// B=4, NV=50000, NRINGS=3, NDIRS=16, NF=16. All f32 except expmap(int32).
// MFMA: per vertex D[16d x 16f] = A[16d x 144k] * W[144k x 16f], k = dd*9 + q.
// R16: TWO-PASS split. 9 rounds showed an invariant ~2TB/s equilibrium with
// all SQ pipes <27% across every single-kernel structure: the latency-bound
// random-gather phase and the BW-bound 1KB/vertex write stream poison each
// other (stream sweeps L2 -> bp evicted -> gathers go long-latency while
// competing with write drain). Split:
//   Pass1 gather_rot: (vertex,dir) threads, no LDS/barrier; computes val[9]
//     (bit-identical math) -> DENSE yw (144 u16/vertex, yl3 element order,
//     28.8MB). Small sweep -> bp stays L2-resident -> gathers are L2 hits.
//   Pass2 mm_store: 1-wave blocks, 8 vertices; 9 perfectly-coalesced dword
//     loads/lane from yw -> in-register expansion into the PROVEN two-parity-
//     copy LDS layout -> untouched fragment reads/MFMA/epilogue. Pure stream.
// ws guard: needs 8192 + 57.6MB; falls back to R12 single-pass otherwise.
// Carried: CP1=295 bank fix, 3-scalar-dword gather, R6 epilogue.
// Closed: operand swap (R9), LDS-transpose epilogue (R10), gather widening
// (R11/R13), 2-wave blocks (R14), NT hints (R15: +40MB write amplification).
#define NBATCH 4
#define NV     50000
#define VST    304         // per-vertex stride = 2*VST u16
#define CP1    295         // copy-1 element offset: odd, ==7 mod 32
#define VPB2   8           // pass2: vertices per 1-wave block
#define VPBF   4           // fallback: vertices per 1-wave block

typedef __attribute__((ext_vector_type(8))) short short8;
typedef __attribute__((ext_vector_type(4))) float floatx4;

// ---- pre-kernel: build per-lane W fragments (bf16) into d_ws ----
__global__ void build_wfrag(const float* __restrict__ kw,
                            unsigned short* __restrict__ wbuf) {
    const int lane = threadIdx.x;
    const int fcol = lane & 15;
    const int quad = lane >> 4;
    #pragma unroll
    for (int kc = 0; kc < 5; ++kc) {
        unsigned short v[8];
        #pragma unroll
        for (int j = 0; j < 8; ++j) {
            int k = kc * 32 + quad * 8 + j;
            unsigned short b = 0;
            if (k < 144) {
                int dd = k / 9;
                int q  = k - dd * 9;
                int r  = q / 3;
                int c  = q - r * 3;
                __hip_bfloat16 h = __float2bfloat16(kw[((r * 16 + dd) * 3 + c) * 16 + fcol]);
                __builtin_memcpy(&b, &h, 2);
            }
            v[j] = b;
        }
        __builtin_memcpy(wbuf + lane * 40 + kc * 8, v, 16);
    }
}

// ---- helper: compute val[9] for (bv, dir) -- IDENTICAL math to R6..R15 ----
__device__ __forceinline__ void compute_val(const float* __restrict__ bp,
                                            const float* __restrict__ fr,
                                            const int2* __restrict__ em,
                                            int bv, int dir,
                                            unsigned short val[9]) {
    float F[9];
    __builtin_memcpy(&F[0], fr + (size_t)bv * 9, 16);
    __builtin_memcpy(&F[4], fr + (size_t)bv * 9 + 4, 16);
    F[8] = fr[(size_t)bv * 9 + 8];
    const float c0 = bp[bv * 3 + 0];
    const float c1 = bp[bv * 3 + 1];
    const float c2 = bp[bv * 3 + 2];
    #pragma unroll
    for (int r = 0; r < 3; ++r) {
        int2 e  = em[bv * 48 + r * 16 + dir];
        int nb  = e.x * NV + e.y;
        float dx = bp[nb * 3 + 0] - c0;
        float dy = bp[nb * 3 + 1] - c1;
        float dz = bp[nb * 3 + 2] - c2;
        #pragma unroll
        for (int c = 0; c < 3; ++c) {
            float yv = F[c * 3 + 0] * dx + F[c * 3 + 1] * dy + F[c * 3 + 2] * dz;
            __hip_bfloat16 h = __float2bfloat16(yv);
            unsigned short us;
            __builtin_memcpy(&us, &h, 2);
            val[r * 3 + c] = us;
        }
    }
}

// ---- pass 1: gather + rotate -> dense yw[bv*144 + dir*9 + c] (yl3 order) ----
__global__ __launch_bounds__(256, 4)
void gather_rot(const float* __restrict__ bp,
                const float* __restrict__ fr,
                const int2*  __restrict__ em,
                unsigned short* __restrict__ yw) {
    const int tid = threadIdx.x;
    const int bv  = blockIdx.x * 16 + (tid >> 4);
    const int dir = tid & 15;
    unsigned short val[9];
    compute_val(bp, fr, em, bv, dir, val);
    // parity-packed 18B group store (same trick as the proven LDS staging)
    unsigned int pe[4], po[4];
    #pragma unroll
    for (int i = 0; i < 4; ++i) {
        pe[i] = (unsigned int)val[2 * i]     | ((unsigned int)val[2 * i + 1] << 16);
        po[i] = (unsigned int)val[2 * i + 1] | ((unsigned int)val[2 * i + 2] << 16);
    }
    unsigned short* wv = yw + (size_t)bv * 144;
    const int n0 = dir * 9;                 // parity == dir parity (bv*144 even)
    if (dir & 1) {                          // odd start: u16 head + 4 dwords
        wv[n0] = val[0];
        unsigned int* p = (unsigned int*)(wv + n0 + 1);
        p[0] = po[0]; p[1] = po[1]; p[2] = po[2]; p[3] = po[3];
    } else {                                // even start: 4 dwords + u16 tail
        unsigned int* p = (unsigned int*)(wv + n0);
        p[0] = pe[0]; p[1] = pe[1]; p[2] = pe[2]; p[3] = pe[3];
        wv[n0 + 8] = val[8];
    }
}

// ---- pass 2: coalesced yw read -> 2-copy LDS -> MFMA -> out ----
__global__ __launch_bounds__(64, 4)
void mm_store(const unsigned short* __restrict__ yw,
              const unsigned short* __restrict__ wbuf,
              const float* __restrict__ bias,
              float*       __restrict__ out) {
    __shared__ __align__(16) unsigned short yls[VPB2 * 2 * VST];   // 9728 B

    const int lane = threadIdx.x;          // 0..63
    const int bv0  = blockIdx.x * VPB2;
    const int fcol = lane & 15;
    const int quad = lane >> 4;

    union WU { unsigned short s[8]; short8 v; };
    WU wf[5];
    const unsigned short* wl = wbuf + lane * 40;
    #pragma unroll
    for (int kc = 0; kc < 5; ++kc)
        __builtin_memcpy(&wf[kc].s[0], wl + kc * 8, 16);
    const float bsf = bias[fcol];

    // 8 vertices x 144 u16 = 576 u32; lane loads p = lane + j*64 (coalesced)
    unsigned int w9[9];
    const unsigned int* src = (const unsigned int*)(yw + (size_t)bv0 * 144);
    #pragma unroll
    for (int j = 0; j < 9; ++j) w9[j] = src[lane + j * 64];

    // expand into the PROVEN layout: copy0 [0,144) + dup [144,279);
    // copy1 at CP1 (odd) with same content. u32 = elements (t, t+1), t even.
    // dup rule: element e duplicated iff e <= 134 (dirs 0..14).
    #pragma unroll
    for (int j = 0; j < 9; ++j) {
        const int p  = lane + j * 64;
        const int v  = p / 72;             // vertex in block
        const int t  = (p - v * 72) * 2;   // element index, even, [0,144)
        const int VB = v * 2 * VST;
        const unsigned int w = w9[j];
        const unsigned short lo = (unsigned short)w;
        const unsigned short hi = (unsigned short)(w >> 16);
        *(unsigned int*)&yls[VB + t] = w;                 // copy0 primary
        yls[VB + CP1 + t]     = lo;                       // copy1 primary
        yls[VB + CP1 + t + 1] = hi;
        if (t <= 132) {                                   // both elems dup'd
            *(unsigned int*)&yls[VB + 144 + t] = w;
            yls[VB + CP1 + 144 + t]     = lo;
            yls[VB + CP1 + 144 + t + 1] = hi;
        } else if (t == 134) {                            // only elem 134
            yls[VB + 278]       = lo;
            yls[VB + CP1 + 278] = lo;
        }
    }
    __syncthreads();   // 1-wave fence (compiler-visible, immediate in HW)

    // ---- MFMA: 8 vertices, 5 chunks each (K=144 exact) -- proven code ----
    floatx4 acc[VPB2];
    #pragma unroll
    for (int i = 0; i < VPB2; ++i) acc[i] = {0.f, 0.f, 0.f, 0.f};
    const unsigned short* abase[VPB2];
    #pragma unroll
    for (int i = 0; i < VPB2; ++i)
        abase[i] = &yls[i * 2 * VST + ((fcol & 1) ? CP1 : 0) + 9 * fcol];
    #pragma unroll
    for (int kc = 0; kc < 4; ++kc) {
        const int s = kc * 32 + quad * 8;
        #pragma unroll
        for (int i = 0; i < VPB2; ++i) {
            const unsigned int* pa = (const unsigned int*)(abase[i] + s);
            union { unsigned int u[4]; short8 s8; } a;
            a.u[0] = pa[0]; a.u[1] = pa[1]; a.u[2] = pa[2]; a.u[3] = pa[3];
            acc[i] = __builtin_amdgcn_mfma_f32_16x16x32_bf16(a.s8, wf[kc].v, acc[i], 0, 0, 0);
        }
    }
    {   // chunk 4: valid k<144 only for quads 0,1.
        const int s = 128 + quad * 8;
        #pragma unroll
        for (int i = 0; i < VPB2; ++i) {
            union { unsigned int u[4]; short8 s8; } a;
            if (quad < 2) {
                const unsigned int* pa = (const unsigned int*)(abase[i] + s);
                a.u[0] = pa[0]; a.u[1] = pa[1]; a.u[2] = pa[2]; a.u[3] = pa[3];
            } else {
                a.u[0] = 0; a.u[1] = 0; a.u[2] = 0; a.u[3] = 0;
            }
            acc[i] = __builtin_amdgcn_mfma_f32_16x16x32_bf16(a.s8, wf[4].v, acc[i], 0, 0, 0);
        }
    }

    // ---- epilogue: proven scattered stores ----
    #pragma unroll
    for (int i = 0; i < VPB2; ++i) {
        int vg = bv0 + i;
        float* ob = out + (size_t)vg * 256;
        #pragma unroll
        for (int rr = 0; rr < 4; ++rr) {
            float o = acc[i][rr] + bsf;
            o = o > 0.f ? o : 0.f;
            ob[(quad * 4 + rr) * 16 + fcol] = o;
        }
    }
}

// ---- fallback: R12 single-pass (127.8us), used if ws too small ----
__global__ __launch_bounds__(64, 8)
void input3d_mfma(const float* __restrict__ bp,
                  const float* __restrict__ fr,
                  const int2*  __restrict__ em,
                  const unsigned short* __restrict__ wbuf,
                  const float* __restrict__ bias,
                  float*       __restrict__ out) {
    __shared__ __align__(16) unsigned short yls[VPBF * 2 * VST];

    const int tid  = threadIdx.x;
    const int bv0  = blockIdx.x * VPBF;
    const int lane = tid;
    const int fcol = lane & 15;
    const int quad = lane >> 4;

    union WU { unsigned short s[8]; short8 v; };
    WU wf[5];
    const unsigned short* wl = wbuf + lane * 40;
    #pragma unroll
    for (int kc = 0; kc < 5; ++kc)
        __builtin_memcpy(&wf[kc].s[0], wl + kc * 8, 16);
    const float bsf = bias[fcol];

    {
        const int v   = tid >> 4;
        const int dir = tid & 15;
        unsigned short val[9];
        compute_val(bp, fr, em, bv0 + v, dir, val);
        unsigned short* buf = &yls[v * 2 * VST];
        unsigned int pe[4], po[4];
        #pragma unroll
        for (int i = 0; i < 4; ++i) {
            pe[i] = (unsigned int)val[2 * i]     | ((unsigned int)val[2 * i + 1] << 16);
            po[i] = (unsigned int)val[2 * i + 1] | ((unsigned int)val[2 * i + 2] << 16);
        }
        const int n0 = dir * 9;
        auto storeE = [&](int s) {
            unsigned int* p = (unsigned int*)(buf + s);
            p[0] = pe[0]; p[1] = pe[1]; p[2] = pe[2]; p[3] = pe[3];
            buf[s + 8] = val[8];
        };
        auto storeO = [&](int s) {
            buf[s] = val[0];
            unsigned int* p = (unsigned int*)(buf + s + 1);
            p[0] = po[0]; p[1] = po[1]; p[2] = po[2]; p[3] = po[3];
        };
        if (dir & 1) {
            storeO(n0);
            storeE(CP1 + n0);
            if (dir < 15) { storeO(n0 + 144); storeE(CP1 + n0 + 144); }
        } else {
            storeE(n0);
            storeO(CP1 + n0);
            if (dir < 15) { storeE(n0 + 144); storeO(CP1 + n0 + 144); }
        }
    }
    __syncthreads();

    floatx4 acc[VPBF] = {{0.f,0.f,0.f,0.f},{0.f,0.f,0.f,0.f},
                         {0.f,0.f,0.f,0.f},{0.f,0.f,0.f,0.f}};
    const unsigned short* abase[VPBF];
    #pragma unroll
    for (int i = 0; i < VPBF; ++i)
        abase[i] = &yls[i * 2 * VST + ((fcol & 1) ? CP1 : 0) + 9 * fcol];
    #pragma unroll
    for (int kc = 0; kc < 4; ++kc) {
        const int s = kc * 32 + quad * 8;
        #pragma unroll
        for (int i = 0; i < VPBF; ++i) {
            const unsigned int* pa = (const unsigned int*)(abase[i] + s);
            union { unsigned int u[4]; short8 s8; } a;
            a.u[0] = pa[0]; a.u[1] = pa[1]; a.u[2] = pa[2]; a.u[3] = pa[3];
            acc[i] = __builtin_amdgcn_mfma_f32_16x16x32_bf16(a.s8, wf[kc].v, acc[i], 0, 0, 0);
        }
    }
    {
        const int s = 128 + quad * 8;
        #pragma unroll
        for (int i = 0; i < VPBF; ++i) {
            union { unsigned int u[4]; short8 s8; } a;
            if (quad < 2) {
                const unsigned int* pa = (const unsigned int*)(abase[i] + s);
                a.u[0] = pa[0]; a.u[1] = pa[1]; a.u[2] = pa[2]; a.u[3] = pa[3];
            } else {
                a.u[0] = 0; a.u[1] = 0; a.u[2] = 0; a.u[3] = 0;
            }
            acc[i] = __builtin_amdgcn_mfma_f32_16x16x32_bf16(a.s8, wf[4].v, acc[i], 0, 0, 0);
        }
    }
    #pragma unroll
    for (int i = 0; i < VPBF; ++i) {
        int vg = bv0 + i;
        float* ob = out + (size_t)vg * 256;
        #pragma unroll
        for (int rr = 0; rr < 4; ++rr) {
            float o = acc[i][rr] + bsf;
            o = o > 0.f ? o : 0.f;
            ob[(quad * 4 + rr) * 16 + fcol] = o;
        }
    }
}

extern "C" void kernel_launch(void* const* d_in, const int* in_sizes, int n_in,
                              void* d_out, int out_size, void* d_ws, size_t ws_size,
                              hipStream_t stream) {
    const float* bp   = (const float*)d_in[0];
    const float* fr   = (const float*)d_in[1];
    const int2*  em   = (const int2*)d_in[2];
    const float* kw   = (const float*)d_in[3];
    const float* bias = (const float*)d_in[4];
    float* out = (float*)d_out;
    unsigned short* wbuf = (unsigned short*)d_ws;   // 5120 B

    build_wfrag<<<1, 64, 0, stream>>>(kw, wbuf);

    const int total_bv = NBATCH * NV;               // 200000
    const size_t need = 8192 + (size_t)total_bv * 144 * 2;   // 57.6 MB + hdr
    if (ws_size >= need) {
        unsigned short* yw = (unsigned short*)((char*)d_ws + 8192);
        gather_rot<<<total_bv / 16, 256, 0, stream>>>(bp, fr, em, yw);
        mm_store<<<total_bv / VPB2, 64, 0, stream>>>(yw, wbuf, bias, out);
    } else {
        input3d_mfma<<<total_bv / VPBF, 64, 0, stream>>>(bp, fr, em, wbuf, bias, out);
    }
}

// Round 11
// 355.491 us; speedup vs baseline: 1.2722x; 1.2722x over previous
//
#include <hip/hip_runtime.h>
#include <hip/hip_bf16.h>

// B=4, NV=50000, NRINGS=3, NDIRS=16, NF=16. All f32 except expmap(int32).
// MFMA: per vertex D[16d x 16f] = A[16d x 144k] * W[144k x 16f], k = dd*9 + q.
// R17 = R12 (1-wave blocks, 127.8us best) + ONE change: BATCH-AFFINE XCD
// SWIZZLE of blockIdx.
//   R16's two-pass decomposition proved: gather phase ~100us standalone,
//   MFMA/store phase ~131us standalone, fused = max (~128us) -- the fused
//   kernel already overlaps the phases across waves. To go faster, a phase
//   must get cheaper. Gather phase is latency-bound on bp reads; em's batch
//   index e.x ALWAYS equals the vertex's own batch (reference: bidx =
//   broadcast(arange(B))), so all gathers of a block stay in one 600KB bp
//   batch-slice. Default dispatch round-robins blocks across 8 XCDs ->
//   every XCD L2 needs all 2.4MB of bp under a 245MB stream sweep -> misses.
//   Swizzle: xcd=bid&7 handles batch xcd>>1 only (2 XCDs/batch, 6250 blocks
//   each) -> per-XCD random-gather hot set = 600KB, L2-resident (each bp
//   line re-touched ~20x per write-sweep period -> LRU keeps it) -> gathers
//   become ~200cyc L2 hits instead of ~500-900cyc L3/HBM.
//   Bijective remap; worst case (XCD assignment not round-robin) loses only
//   locality, never correctness.
// Carried: 1-wave blocks (R12), CP1=295 bank fix (R11), 3-scalar-dword
// gather, R6 epilogue, __syncthreads as the LDS fence.
// Closed: operand swap (R9), LDS-transpose epilogue (R10), gather widening
// (R11/R13 x2), 2-wave blocks (R14), NT hints (R15, +40MB write ampl.),
// two-pass split (R16, sum not max).
#define NBATCH 4
#define NV     50000
#define VPB    4           // vertices per block (1 wave x 4 vertices)
#define VST    304         // per-vertex stride = 2*VST elems
#define CP1    295         // copy-1 element offset: odd, ==7 mod 32 (bank fix)
#define BPB    6250        // blocks per (batch-half): NV/VPB/2

typedef __attribute__((ext_vector_type(8))) short short8;
typedef __attribute__((ext_vector_type(4))) float floatx4;

// ---- pre-kernel: build per-lane W fragments (bf16) into d_ws ----
// layout: lane*40 + kc*8 ushorts (16B per chunk, 80B per lane, 5120B total)
__global__ void build_wfrag(const float* __restrict__ kw,
                            unsigned short* __restrict__ wbuf) {
    const int lane = threadIdx.x;      // 0..63
    const int fcol = lane & 15;
    const int quad = lane >> 4;
    #pragma unroll
    for (int kc = 0; kc < 5; ++kc) {
        unsigned short v[8];
        #pragma unroll
        for (int j = 0; j < 8; ++j) {
            int k = kc * 32 + quad * 8 + j;
            unsigned short b = 0;
            if (k < 144) {
                int dd = k / 9;
                int q  = k - dd * 9;
                int r  = q / 3;
                int c  = q - r * 3;
                __hip_bfloat16 h = __float2bfloat16(kw[((r * 16 + dd) * 3 + c) * 16 + fcol]);
                __builtin_memcpy(&b, &h, 2);
            }
            v[j] = b;
        }
        __builtin_memcpy(wbuf + lane * 40 + kc * 8, v, 16);
    }
}

__global__ __launch_bounds__(64, 8)
void input3d_mfma(const float* __restrict__ bp,     // (B,NV,3)
                  const float* __restrict__ fr,     // (B,NV,3,3)
                  const int2*  __restrict__ em,     // (B,NV,3,16) int pairs
                  const unsigned short* __restrict__ wbuf, // prebuilt W frags
                  const float* __restrict__ bias,   // (16)
                  float*       __restrict__ out)    // (B,NV,16,16)
{
    __shared__ __align__(16) unsigned short yls[VPB * 2 * VST];   // 4864 B

    const int tid  = threadIdx.x;      // 0..63 (one wave)
    // ---- batch-affine XCD swizzle (R17): XCD x -> batch x>>1 only ----
    const int bid   = blockIdx.x;
    const int xcd   = bid & 7;
    const int slot  = bid >> 3;                      // 0..6249
    const int bv0   = (xcd >> 1) * NV + (((xcd & 1) * BPB) + slot) * VPB;
    const int lane = tid;
    const int fcol = lane & 15;
    const int quad = lane >> 4;

    // ---- load prebuilt W fragments: 5 x dwordx4 ----
    union WU { unsigned short s[8]; short8 v; };
    WU wf[5];
    const unsigned short* wl = wbuf + lane * 40;
    #pragma unroll
    for (int kc = 0; kc < 5; ++kc)
        __builtin_memcpy(&wf[kc].s[0], wl + kc * 8, 16);
    const float bsf = bias[fcol];

    // ---- staging: thread = (v = tid>>4, dir = tid&15) ----
    {
        const int v   = tid >> 4;      // 0..3
        const int dir = tid & 15;
        const int bv  = bv0 + v;
        float F[9];
        __builtin_memcpy(&F[0], fr + (size_t)bv * 9, 16);
        __builtin_memcpy(&F[4], fr + (size_t)bv * 9 + 4, 16);
        F[8] = fr[(size_t)bv * 9 + 8];
        const float c0 = bp[bv * 3 + 0];
        const float c1 = bp[bv * 3 + 1];
        const float c2 = bp[bv * 3 + 2];

        unsigned short val[9];
        #pragma unroll
        for (int r = 0; r < 3; ++r) {
            int2 e  = em[bv * 48 + r * 16 + dir];
            int nb  = e.x * NV + e.y;
            float dx = bp[nb * 3 + 0] - c0;
            float dy = bp[nb * 3 + 1] - c1;
            float dz = bp[nb * 3 + 2] - c2;
            #pragma unroll
            for (int c = 0; c < 3; ++c) {
                float yv = F[c * 3 + 0] * dx + F[c * 3 + 1] * dy + F[c * 3 + 2] * dz;
                __hip_bfloat16 h = __float2bfloat16(yv);
                unsigned short us;
                __builtin_memcpy(&us, &h, 2);
                val[r * 3 + c] = us;
            }
        }

        // packed 9-element group writes (4 x b32 + 1 x u16 per group)
        unsigned short* buf = &yls[v * 2 * VST];
        unsigned int pe[4], po[4];
        #pragma unroll
        for (int i = 0; i < 4; ++i) {
            pe[i] = (unsigned int)val[2 * i]     | ((unsigned int)val[2 * i + 1] << 16);
            po[i] = (unsigned int)val[2 * i + 1] | ((unsigned int)val[2 * i + 2] << 16);
        }
        const int n0 = dir * 9;
        // even-start group: dwords at s, tail u16 at s+8
        auto storeE = [&](int s) {
            unsigned int* p = (unsigned int*)(buf + s);
            p[0] = pe[0]; p[1] = pe[1]; p[2] = pe[2]; p[3] = pe[3];
            buf[s + 8] = val[8];
        };
        // odd-start group: head u16 at s, dwords at s+1
        auto storeO = [&](int s) {
            buf[s] = val[0];
            unsigned int* p = (unsigned int*)(buf + s + 1);
            p[0] = po[0]; p[1] = po[1]; p[2] = po[2]; p[3] = po[3];
        };
        if (dir & 1) {                 // n0 odd
            storeO(n0);
            storeE(CP1 + n0);          // 295+odd = even start
            if (dir < 15) { storeO(n0 + 144); storeE(CP1 + n0 + 144); }
        } else {                       // n0 even
            storeE(n0);
            storeO(CP1 + n0);          // 295+even = odd start
            if (dir < 15) { storeE(n0 + 144); storeO(CP1 + n0 + 144); }
        }
    }
    // single-wave workgroup: s_barrier is immediate; kept purely as a
    // correct, compiler-visible memory fence for the LDS write->read handoff.
    __syncthreads();

    // ---- this wave: 4 vertices, 5 MFMA each (K=144 exact) ----
    floatx4 acc[4] = {{0.f,0.f,0.f,0.f},{0.f,0.f,0.f,0.f},
                      {0.f,0.f,0.f,0.f},{0.f,0.f,0.f,0.f}};
    const unsigned short* abase[4];
    #pragma unroll
    for (int i = 0; i < 4; ++i) {
        abase[i] = &yls[i * 2 * VST + ((fcol & 1) ? CP1 : 0) + 9 * fcol];
    }
    #pragma unroll
    for (int kc = 0; kc < 4; ++kc) {
        const int s = kc * 32 + quad * 8;
        #pragma unroll
        for (int i = 0; i < 4; ++i) {
            const unsigned int* pa = (const unsigned int*)(abase[i] + s);
            union { unsigned int u[4]; short8 s8; } a;
            a.u[0] = pa[0]; a.u[1] = pa[1]; a.u[2] = pa[2]; a.u[3] = pa[3];
            acc[i] = __builtin_amdgcn_mfma_f32_16x16x32_bf16(a.s8, wf[kc].v, acc[i], 0, 0, 0);
        }
    }
    {   // chunk 4: k = 128 + quad*8 + j; valid k<144 only for quads 0,1.
        const int s = 128 + quad * 8;
        #pragma unroll
        for (int i = 0; i < 4; ++i) {
            union { unsigned int u[4]; short8 s8; } a;
            if (quad < 2) {
                const unsigned int* pa = (const unsigned int*)(abase[i] + s);
                a.u[0] = pa[0]; a.u[1] = pa[1]; a.u[2] = pa[2]; a.u[3] = pa[3];
            } else {
                a.u[0] = 0; a.u[1] = 0; a.u[2] = 0; a.u[3] = 0;
            }
            acc[i] = __builtin_amdgcn_mfma_f32_16x16x32_bf16(a.s8, wf[4].v, acc[i], 0, 0, 0);
        }
    }

    // ---- epilogue: R6 scattered stores (proven fine; not the bottleneck) ----
    // C layout col=lane&15=f, row=quad*4+reg=d -> direct store. Each inst
    // covers 4 complete 64B lines (verified: WRITE_SIZE == exact 200MB).
    #pragma unroll
    for (int i = 0; i < 4; ++i) {
        int vg = bv0 + i;
        float* ob = out + (size_t)vg * 256;
        #pragma unroll
        for (int rr = 0; rr < 4; ++rr) {
            float o = acc[i][rr] + bsf;
            o = o > 0.f ? o : 0.f;
            ob[(quad * 4 + rr) * 16 + fcol] = o;
        }
    }
}

extern "C" void kernel_launch(void* const* d_in, const int* in_sizes, int n_in,
                              void* d_out, int out_size, void* d_ws, size_t ws_size,
                              hipStream_t stream) {
    const float* bp   = (const float*)d_in[0];
    const float* fr   = (const float*)d_in[1];
    const int2*  em   = (const int2*)d_in[2];
    const float* kw   = (const float*)d_in[3];
    const float* bias = (const float*)d_in[4];
    float* out = (float*)d_out;
    unsigned short* wbuf = (unsigned short*)d_ws;   // 5120 B used

    build_wfrag<<<1, 64, 0, stream>>>(kw, wbuf);

    const int total_bv = NBATCH * NV;          // 200000
    const int grid = total_bv / VPB;           // 50000 blocks (1 wave each)
    input3d_mfma<<<grid, 64, 0, stream>>>(bp, fr, em, wbuf, bias, out);
}